// Round 1
// baseline (282.352 us; speedup 1.0000x reference)
//
#include <hip/hip_runtime.h>
#include <math.h>

#define B_ 2048
#define N_ 256
#define R_ (B_*N_)
#define MU_ 0.1f
#define SIGMA_ 0.2f
#define LDH 264   // 256 + 8 shorts pad (16B) -> row stride 528B, 4-bank rotation

typedef __attribute__((ext_vector_type(8))) short bf16x8;
typedef __attribute__((ext_vector_type(4))) float f32x4;

__device__ __forceinline__ unsigned short f2bf(float x) {
    union { float f; unsigned u; } v; v.f = x;
    unsigned r = v.u + 0x7fffu + ((v.u >> 16) & 1u);   // RNE, inputs finite
    return (unsigned short)(r >> 16);
}

// ---- convert fW1/gW1 (256x256 f32, k-major) to bf16 in MFMA B-fragment layout ----
// dest short idx = ((kk*16 + ntile)*64 + lane)*8 + j ; k = kk*32 + (lane>>4)*8 + j ; n = ntile*16 + (lane&15)
__global__ void prep_weights(const float* __restrict__ fW1, const float* __restrict__ gW1,
                             unsigned short* __restrict__ wswz) {
    int idx = blockIdx.x * 256 + threadIdx.x;
    if (idx >= 2 * 65536) return;
    int m = idx >> 16, r = idx & 65535;
    int j = r & 7, lane = (r >> 3) & 63, frag = r >> 9;
    int kk = frag >> 4, nt = frag & 15;
    int k = kk * 32 + (lane >> 4) * 8 + j;
    int n = nt * 16 + (lane & 15);
    const float* W = m ? gW1 : fW1;
    wswz[idx] = f2bf(W[k * 256 + n]);
}

// ---- Euler-Maruyama trajectory: one thread per batch element ----
__global__ void traj_kernel(const float* __restrict__ ts, const float* __restrict__ x0,
                            const float* __restrict__ eps, float* __restrict__ xs,
                            float* __restrict__ fv) {
    int b = blockIdx.x * blockDim.x + threadIdx.x;
    if (b >= B_) return;
    float x1 = x0[2*b], x2 = x0[2*b+1];
    xs[(b*N_)*2]   = x1;
    xs[(b*N_)*2+1] = x2;
    for (int n = 0; n < N_-1; ++n) {
        float h = ts[n+1] - ts[n];
        float sdt = sqrtf(h);
        float dw0 = eps[(b*N_+n)*2]   * sdt;
        float dw1 = eps[(b*N_+n)*2+1] * sdt;
        x1 = (x1 + (MU_*x1)*h) + (SIGMA_*x1)*dw0;
        x2 = (x2 + (MU_*x2)*h) + (SIGMA_*x2)*dw1;
        xs[(b*N_+n+1)*2]   = x1;
        xs[(b*N_+n+1)*2+1] = x2;
    }
    fv[b] = x1*x1 + x2*x2;
}

// ---- fused MLP: layer0 (VALU) -> layer1 (MFMA, W1 resident in VGPRs) -> layer2 (reduce) ----
__global__ __launch_bounds__(256, 2) void mlp_kernel(
        const float* __restrict__ ts, const float* __restrict__ eps, const float* __restrict__ xs,
        const unsigned short* __restrict__ wswz,
        const float* __restrict__ fW0, const float* __restrict__ fb0, const float* __restrict__ fb1,
        const float* __restrict__ fW2, const float* __restrict__ fb2,
        const float* __restrict__ gW0, const float* __restrict__ gb0, const float* __restrict__ gb1,
        const float* __restrict__ gW2, const float* __restrict__ gb2,
        float* __restrict__ Yout, float* __restrict__ zdot) {

    __shared__ __align__(16) unsigned short h0s[16 * LDH];
    __shared__ float tx0[16], tx1[16], tx2[16], dws0[16], dws1[16];
    __shared__ float red[4][16];

    const int tid  = threadIdx.x;
    const int lane = tid & 63;
    const int w    = tid >> 6;       // wave id: cols [64w, 64w+64)
    const int arow = lane & 15;      // A row / output col-within-ntile
    const int rg   = lane >> 4;      // k-group for A/B, row-group for C/D

    for (int mlp = 0; mlp < 2; ++mlp) {
        const float* W0  = mlp ? gW0 : fW0;
        const float* b0p = mlp ? gb0 : fb0;
        const float* b1p = mlp ? gb1 : fb1;
        // per-thread layer0 column weights (col = tid), hoisted across all tiles
        float w00 = W0[tid], w01 = W0[256 + tid], w02 = W0[512 + tid], bb0 = b0p[tid];
        // per-lane layer1 bias + layer2 weights for this wave's 4 col-tiles
        float b1c[4], w20[4], w21[4];
#pragma unroll
        for (int nt = 0; nt < 4; ++nt) {
            int c = w * 64 + nt * 16 + arow;
            b1c[nt] = b1p[c];
            if (mlp) { w20[nt] = gW2[2*c]; w21[nt] = gW2[2*c+1]; }
            else     { w20[nt] = fW2[c];   w21[nt] = 0.f; }
        }
        float bias20 = mlp ? gb2[0] : fb2[0];
        float bias21 = mlp ? gb2[1] : 0.f;

        // resident B fragments of W1: 8 k-steps x 4 n-tiles x 4 VGPR = 128 VGPRs
        bf16x8 bfrag[8][4];
        const bf16x8* wsw8 = (const bf16x8*)(wswz + mlp * 65536);
#pragma unroll
        for (int kk = 0; kk < 8; ++kk)
#pragma unroll
            for (int nt = 0; nt < 4; ++nt)
                bfrag[kk][nt] = wsw8[(kk * 16 + (w * 4 + nt)) * 64 + lane];

        for (int rt = blockIdx.x; rt < R_ / 16; rt += gridDim.x) {
            const int rowbase = rt * 16;
            const int n0 = rowbase & (N_ - 1);
            __syncthreads();   // protect tx/dws/red from previous tile's readers
            if (tid < 16) {
                int n = n0 + tid, r = rowbase + tid;
                tx0[tid] = ts[n];
                tx1[tid] = xs[2*r];
                tx2[tid] = xs[2*r+1];
                if (mlp) {
                    float d0 = 0.f, d1 = 0.f;
                    if (n < N_-1) {
                        float sdt = sqrtf(ts[n+1] - ts[n]);
                        d0 = eps[2*r]   * sdt;
                        d1 = eps[2*r+1] * sdt;
                    }
                    dws0[tid] = d0; dws1[tid] = d1;
                }
            }
            __syncthreads();
            // layer0: each thread computes its col (tid) for all 16 rows
#pragma unroll
            for (int i = 0; i < 16; ++i) {
                float h = fmaf(tx0[i], w00, fmaf(tx1[i], w01, fmaf(tx2[i], w02, bb0)));
                h0s[i * LDH + tid] = f2bf(fmaxf(h, 0.f));
            }
            __syncthreads();
            // layer1: 16x256 = A(16x256bf16, LDS) @ W1(VGPR frags)
            f32x4 acc0 = {0,0,0,0}, acc1 = {0,0,0,0}, acc2 = {0,0,0,0}, acc3 = {0,0,0,0};
#pragma unroll
            for (int kk = 0; kk < 8; ++kk) {
                bf16x8 a = *(const bf16x8*)&h0s[arow * LDH + kk * 32 + rg * 8];
                acc0 = __builtin_amdgcn_mfma_f32_16x16x32_bf16(a, bfrag[kk][0], acc0, 0, 0, 0);
                acc1 = __builtin_amdgcn_mfma_f32_16x16x32_bf16(a, bfrag[kk][1], acc1, 0, 0, 0);
                acc2 = __builtin_amdgcn_mfma_f32_16x16x32_bf16(a, bfrag[kk][2], acc2, 0, 0, 0);
                acc3 = __builtin_amdgcn_mfma_f32_16x16x32_bf16(a, bfrag[kk][3], acc3, 0, 0, 0);
            }
            // layer2: bias+relu then weighted col-sum; acc[nt][i] -> row rg*4+i, col w*64+nt*16+arow
            float s0 = 0.f, s1 = 0.f, s2 = 0.f, s3 = 0.f;
            if (mlp == 0) {
#pragma unroll
                for (int nt = 0; nt < 4; ++nt) {
                    f32x4 a = nt==0?acc0:nt==1?acc1:nt==2?acc2:acc3;
                    s0 = fmaf(fmaxf(a[0] + b1c[nt], 0.f), w20[nt], s0);
                    s1 = fmaf(fmaxf(a[1] + b1c[nt], 0.f), w20[nt], s1);
                    s2 = fmaf(fmaxf(a[2] + b1c[nt], 0.f), w20[nt], s2);
                    s3 = fmaf(fmaxf(a[3] + b1c[nt], 0.f), w20[nt], s3);
                }
            } else {
                // fold Z·dW: weight per (row,col) = W2[c,0]*dw0[row] + W2[c,1]*dw1[row]
                float d00 = dws0[rg*4+0], d01 = dws0[rg*4+1], d02 = dws0[rg*4+2], d03 = dws0[rg*4+3];
                float d10 = dws1[rg*4+0], d11 = dws1[rg*4+1], d12 = dws1[rg*4+2], d13 = dws1[rg*4+3];
#pragma unroll
                for (int nt = 0; nt < 4; ++nt) {
                    f32x4 a = nt==0?acc0:nt==1?acc1:nt==2?acc2:acc3;
                    s0 = fmaf(fmaxf(a[0] + b1c[nt], 0.f), fmaf(w21[nt], d10, w20[nt]*d00), s0);
                    s1 = fmaf(fmaxf(a[1] + b1c[nt], 0.f), fmaf(w21[nt], d11, w20[nt]*d01), s1);
                    s2 = fmaf(fmaxf(a[2] + b1c[nt], 0.f), fmaf(w21[nt], d12, w20[nt]*d02), s2);
                    s3 = fmaf(fmaxf(a[3] + b1c[nt], 0.f), fmaf(w21[nt], d13, w20[nt]*d03), s3);
                }
            }
            // reduce over the 16 cols held across lanes (same 16-lane cluster)
#pragma unroll
            for (int m = 1; m < 16; m <<= 1) {
                s0 += __shfl_xor(s0, m);
                s1 += __shfl_xor(s1, m);
                s2 += __shfl_xor(s2, m);
                s3 += __shfl_xor(s3, m);
            }
            if (arow == 0) {
                red[w][rg*4+0] = s0; red[w][rg*4+1] = s1;
                red[w][rg*4+2] = s2; red[w][rg*4+3] = s3;
            }
            __syncthreads();
            if (tid < 16) {
                float v = red[0][tid] + red[1][tid] + red[2][tid] + red[3][tid];
                if (mlp == 0) Yout[rowbase + tid] = v + bias20;
                else          zdot[rowbase + tid] = v + fmaf(bias21, dws1[tid], bias20 * dws0[tid]);
            }
        }
    }
}

// ---- loss: sum over r of (Y + Zdot - target)^2, /B ----
__global__ void loss_partial_kernel(const float* __restrict__ Yout, const float* __restrict__ fv,
                                    const float* __restrict__ zdot, float* __restrict__ partials) {
    __shared__ float wred[4];
    int tid = threadIdx.x;
    float s = 0.f;
    for (int r = blockIdx.x * 256 + tid; r < R_; r += gridDim.x * 256) {
        int n = r & (N_ - 1);
        float pred = Yout[r] + zdot[r];
        float target = (n == N_ - 1) ? fv[r >> 8] : Yout[r + 1];
        float d = pred - target;
        s = fmaf(d, d, s);
    }
#pragma unroll
    for (int m = 1; m < 64; m <<= 1) s += __shfl_xor(s, m);
    if ((tid & 63) == 0) wred[tid >> 6] = s;
    __syncthreads();
    if (tid == 0) partials[blockIdx.x] = wred[0] + wred[1] + wred[2] + wred[3];
}

__global__ void loss_final_kernel(const float* __restrict__ partials, float* __restrict__ out) {
    __shared__ float wred[4];
    int tid = threadIdx.x;
    float s = partials[tid] + partials[256 + tid] + partials[512 + tid] + partials[768 + tid];
#pragma unroll
    for (int m = 1; m < 64; m <<= 1) s += __shfl_xor(s, m);
    if ((tid & 63) == 0) wred[tid >> 6] = s;
    __syncthreads();
    if (tid == 0) out[0] = (wred[0] + wred[1] + wred[2] + wred[3]) * (1.0f / B_);
}

extern "C" void kernel_launch(void* const* d_in, const int* in_sizes, int n_in,
                              void* d_out, int out_size, void* d_ws, size_t ws_size,
                              hipStream_t stream) {
    const float* ts  = (const float*)d_in[0];
    const float* x0  = (const float*)d_in[1];
    const float* eps = (const float*)d_in[2];
    const float* fW0 = (const float*)d_in[3];
    const float* fb0 = (const float*)d_in[4];
    const float* fW1 = (const float*)d_in[5];
    const float* fb1 = (const float*)d_in[6];
    const float* fW2 = (const float*)d_in[7];
    const float* fb2 = (const float*)d_in[8];
    const float* gW0 = (const float*)d_in[9];
    const float* gb0 = (const float*)d_in[10];
    const float* gW1 = (const float*)d_in[11];
    const float* gb1 = (const float*)d_in[12];
    const float* gW2 = (const float*)d_in[13];
    const float* gb2 = (const float*)d_in[14];

    float* out = (float*)d_out;
    float* Yout = out + 1;            // Y: (B,N,1) flat = row index b*N+n
    float* fv   = out + 1 + R_;       // final_value: (B,1)

    char* wsb = (char*)d_ws;
    float* xs             = (float*)wsb;                                    // B*N*2 f32 = 4MB
    unsigned short* wswz  = (unsigned short*)(wsb + (4 << 20));             // 2*65536 bf16 = 256KB
    float* zdot           = (float*)(wsb + (4 << 20) + (256 << 10));        // R f32 = 2MB
    float* partials       = (float*)(wsb + (4 << 20) + (256 << 10) + (2 << 20)); // 1024 f32

    hipLaunchKernelGGL(prep_weights, dim3(512), dim3(256), 0, stream, fW1, gW1, wswz);
    hipLaunchKernelGGL(traj_kernel, dim3(8), dim3(256), 0, stream, ts, x0, eps, xs, fv);
    hipLaunchKernelGGL(mlp_kernel, dim3(1024), dim3(256), 0, stream,
                       ts, eps, xs, wswz, fW0, fb0, fb1, fW2, fb2,
                       gW0, gb0, gb1, gW2, gb2, Yout, zdot);
    hipLaunchKernelGGL(loss_partial_kernel, dim3(1024), dim3(256), 0, stream, Yout, fv, zdot, partials);
    hipLaunchKernelGGL(loss_final_kernel, dim3(1), dim3(256), 0, stream, partials, out);
}